// Round 7
// baseline (94.968 us; speedup 1.0000x reference)
//
#include <hip/hip_runtime.h>

typedef __attribute__((ext_vector_type(8))) short short8;
typedef __attribute__((ext_vector_type(4))) short bf16x4;
typedef __attribute__((ext_vector_type(4))) float f32x4;
typedef unsigned short ushort_t;

#define MFMA(a, b, c) __builtin_amdgcn_mfma_f32_16x16x32_bf16((a), (b), (c), 0, 0, 0)

constexpr int NB = 32, NHt = 128, NWd = 128, NC = 64, MX = 32;
constexpr float TWO_PI = 6.28318530717958647692f;

// workspace layout (64 KB tables + 8 MiB X/Y buffer)
constexpr size_t TAB_T3 = 32768;  // K3 stage4 B: G64 inv [nt4][ks2][lane64][re8,im8]
constexpr size_t TAB_T4 = 49152;  // K3 stage5 B: G128 inv [wt8][lane64][re8, NEG-im8] (x 2^-13)
constexpr size_t XY_OFF = 65536;  // X then Y in-place: bf16 [h32][u32][comp2][b32][k64]

__device__ inline ushort_t f2bf(float f) {
    union { float f; unsigned int u; } v; v.f = f;
    unsigned int r = v.u + 0x7FFFu + ((v.u >> 16) & 1u);   // RTN-even
    return (ushort_t)(r >> 16);
}
// row-dependent XOR swizzle (bits 4-5), 16B-granular.
__device__ inline int sxor(int row) { return ((row >> 3) & 3) << 4; }

// ---------------------------------------------------------------------------
// K1: per (b, h<32). M1 = F128trunc . x  (32x64 cplx), X = M1 . G64fwd.
// Twiddles inline; lead block emits K3's T3/T4 tables into the workspace.
// ---------------------------------------------------------------------------
__global__ __launch_bounds__(512) void k1_fwd(
    const float* __restrict__ x, char* __restrict__ tabs, ushort_t* __restrict__ XY)
{
    const int b = blockIdx.x, h = blockIdx.y;
    const int tid = threadIdx.x, lane = tid & 63, wv = tid >> 6;
    constexpr int SXT  = 0;            // x^T bf16 [c64][w128], stride 272B; reused for X-out
    constexpr int M1RE = 17408;        // [u32][c64+pad], stride 144B
    constexpr int M1IM = 17408 + 4608;
    __shared__ __align__(16) char sm[26624];

    // ---- lead block: emit T3/T4 tables for k3 (512 entries each) ----
    if (b == 0 && h == 0) {
        {   // T3: G64 inv  exp(+2pi i o c/64); entry = tid
            int nt2 = tid >> 7, ks2 = (tid >> 6) & 1, l = tid & 63;
            int cc2 = (l & 15) + 16 * nt2, ob = (l >> 4) * 8 + 32 * ks2;
            short8 vre, vim;
            #pragma unroll
            for (int j = 0; j < 8; ++j) {
                float a = (float)(((ob + j) * cc2) & 63) * (TWO_PI / 64.f);
                float s, c; __sincosf(a, &s, &c);
                vre[j] = (short)f2bf(c); vim[j] = (short)f2bf(s);
            }
            *reinterpret_cast<short8*>(tabs + TAB_T3 + tid * 32)      = vre;
            *reinterpret_cast<short8*>(tabs + TAB_T3 + tid * 32 + 16) = vim;
        }
        {   // T4: G128 inv exp(+2pi i w u/128) * 2^-13; im PRE-NEGATED; entry = tid
            int wt = tid >> 6, l = tid & 63;
            int w = (l & 15) + 16 * wt, ub = (l >> 4) * 8;
            short8 vre, vim;
            #pragma unroll
            for (int j = 0; j < 8; ++j) {
                float a = (float)((w * (ub + j)) & 127) * (TWO_PI / 128.f);
                float s, c; __sincosf(a, &s, &c);
                vre[j] = (short)f2bf(c * 0.0001220703125f);   // exact 2^-13
                vim[j] = (short)f2bf(-s * 0.0001220703125f);  // negated for fused MFMA
            }
            *reinterpret_cast<short8*>(tabs + TAB_T4 + tid * 32)      = vre;
            *reinterpret_cast<short8*>(tabs + TAB_T4 + tid * 32 + 16) = vim;
        }
    }

    // ---- load x slice (float4) + transpose -> sxT[c][w] bf16 (swizzled) ----
    const float* xs = x + ((size_t)(b * NHt + h)) * (NWd * NC);
    #pragma unroll
    for (int i = 0; i < 4; ++i) {
        int idx = tid + 512 * i;               // 0..2047 float4s
        int w = idx >> 4, c4 = (idx & 15) * 4;
        f32x4 v = *reinterpret_cast<const f32x4*>(xs + w * 64 + c4);
        #pragma unroll
        for (int j = 0; j < 4; ++j)
            *(ushort_t*)(sm + SXT + (c4 + j) * 272 + ((w * 2) ^ sxor(c4 + j))) = f2bf(v[j]);
    }
    __syncthreads();

    const int mt = wv >> 2, nt = wv & 3;
    // stage 1: M1[u,c] = sum_w F[u,w] x[w,c]; F-frag computed inline
    f32x4 m1r = {0.f,0.f,0.f,0.f}, m1i = {0.f,0.f,0.f,0.f};
    const int cc = (lane & 15) + 16 * nt;
    const int uu = (lane & 15) + 16 * mt;
    #pragma unroll
    for (int ks = 0; ks < 4; ++ks) {
        short8 bfrag = *reinterpret_cast<const short8*>(
            sm + SXT + cc * 272 + (((lane >> 4) * 16 + 64 * ks) ^ sxor(cc)));
        int wb = (lane >> 4) * 8 + 32 * ks;
        short8 are, aim;
        #pragma unroll
        for (int j = 0; j < 8; ++j) {
            float a = (float)((uu * (wb + j)) & 127) * (TWO_PI / 128.f);
            float s, c; __sincosf(a, &s, &c);
            are[j] = (short)f2bf(c); aim[j] = (short)f2bf(-s);
        }
        m1r = MFMA(are, bfrag, m1r);
        m1i = MFMA(aim, bfrag, m1i);
    }
    #pragma unroll
    for (int r = 0; r < 4; ++r) {
        int u = (lane >> 4) * 4 + r + 16 * mt;
        int c = (lane & 15) + 16 * nt;
        *(ushort_t*)(sm + M1RE + u * 144 + c * 2) = f2bf(m1r[r]);
        *(ushort_t*)(sm + M1IM + u * 144 + c * 2) = f2bf(m1i[r]);
    }
    __syncthreads();

    // stage 2: X[u,k] = sum_c M1[u,c] G64f[c,k]; G-frag inline; out via LDS
    f32x4 xP = {0.f,0.f,0.f,0.f}, xQ = {0.f,0.f,0.f,0.f}, xI = {0.f,0.f,0.f,0.f};
    const int kk = (lane & 15) + 16 * nt;
    #pragma unroll
    for (int ks = 0; ks < 2; ++ks) {
        short8 are = *reinterpret_cast<const short8*>(
            sm + M1RE + ((lane & 15) + 16 * mt) * 144 + (lane >> 4) * 16 + 64 * ks);
        short8 aim = *reinterpret_cast<const short8*>(
            sm + M1IM + ((lane & 15) + 16 * mt) * 144 + (lane >> 4) * 16 + 64 * ks);
        int cb2 = (lane >> 4) * 8 + 32 * ks;
        short8 bre, bim;
        #pragma unroll
        for (int j = 0; j < 8; ++j) {
            float a = (float)((kk * (cb2 + j)) & 63) * (TWO_PI / 64.f);
            float s, c; __sincosf(a, &s, &c);
            bre[j] = (short)f2bf(c); bim[j] = (short)f2bf(-s);
        }
        xP = MFMA(are, bre, xP);
        xQ = MFMA(aim, bim, xQ);
        xI = MFMA(are, bim, xI);
        xI = MFMA(aim, bre, xI);
    }
    #pragma unroll
    for (int r = 0; r < 4; ++r) {
        int u = (lane >> 4) * 4 + r + 16 * mt;
        int k = (lane & 15) + 16 * nt;
        *(ushort_t*)(sm + SXT + 0    + u * 128 + k * 2) = f2bf(xP[r] - xQ[r]);
        *(ushort_t*)(sm + SXT + 4096 + u * 128 + k * 2) = f2bf(xI[r]);
    }
    __syncthreads();

    // coalesced X store: thread -> (u, comp, k8)
    {
        int u = tid >> 4, comp = (tid >> 3) & 1, k8 = (tid & 7) * 8;
        short8 v = *reinterpret_cast<const short8*>(sm + SXT + comp * 4096 + u * 128 + k8 * 2);
        size_t hu = (size_t)(h * 32 + u);
        *reinterpret_cast<short8*>(XY + ((hu * 2 + comp) * 32 + b) * 64 + k8) = v;
    }
}

// ---------------------------------------------------------------------------
// K2: per (h, u). Y[b,o] = sum_k X[b,k] W[h,u,k,o] — b-batched so W is read
// from HBM exactly once.
// ---------------------------------------------------------------------------
__global__ __launch_bounds__(256) void k2_mix(
    const float* __restrict__ wre, const float* __restrict__ wim, ushort_t* __restrict__ XY)
{
    const int h = blockIdx.x, u = blockIdx.y;
    const int tid = threadIdx.x, lane = tid & 63, wv = tid >> 6;   // 4 waves
    constexpr int XRE = 0, XIM = 4608, WTR = 9216, WTI = 18432;    // strides 144B
    __shared__ __align__(16) char sm[27648];
    const size_t hu = (size_t)(h * 32 + u);

    #pragma unroll
    for (int it = 0; it < 2; ++it) {        // stage X[b][k] (both comps)
        int row = (tid >> 3) + 32 * it;
        int comp = row >> 5, bb = row & 31, k8 = (tid & 7) * 8;
        short8 v = *reinterpret_cast<const short8*>(XY + ((hu * 2 + comp) * 32 + bb) * 64 + k8);
        *reinterpret_cast<short8*>(sm + (comp ? XIM : XRE) + bb * 144 + k8 * 2) = v;
    }
    const float* wr = wre + hu * 4096;      // transpose W -> WT[o][k] bf16 (swizzled)
    const float* wi = wim + hu * 4096;
    #pragma unroll
    for (int i = 0; i < 4; ++i) {
        int idx = tid + 256 * i;            // 0..1023
        int k = idx >> 4, o4 = (idx & 15) * 4;
        f32x4 vr = __builtin_nontemporal_load(reinterpret_cast<const f32x4*>(wr + k * 64 + o4));
        f32x4 vi = __builtin_nontemporal_load(reinterpret_cast<const f32x4*>(wi + k * 64 + o4));
        #pragma unroll
        for (int j = 0; j < 4; ++j) {
            int o = o4 + j, koff = (k * 2) ^ sxor(o);
            *(ushort_t*)(sm + WTR + o * 144 + koff) = f2bf(vr[j]);
            *(ushort_t*)(sm + WTI + o * 144 + koff) = f2bf(vi[j]);
        }
    }
    __syncthreads();

    const int mt = wv >> 1;
    f32x4 yRe[2], yIm[2];
    #pragma unroll
    for (int half = 0; half < 2; ++half) {
        const int nt = (wv & 1) * 2 + half;
        const int oo = (lane & 15) + 16 * nt;
        f32x4 yP = {0.f,0.f,0.f,0.f}, yQ = {0.f,0.f,0.f,0.f}, yI = {0.f,0.f,0.f,0.f};
        #pragma unroll
        for (int ks = 0; ks < 2; ++ks) {
            int woff = ((lane >> 4) * 16 + 64 * ks) ^ sxor(oo);
            short8 are = *reinterpret_cast<const short8*>(
                sm + XRE + ((lane & 15) + 16 * mt) * 144 + (lane >> 4) * 16 + 64 * ks);
            short8 aim = *reinterpret_cast<const short8*>(
                sm + XIM + ((lane & 15) + 16 * mt) * 144 + (lane >> 4) * 16 + 64 * ks);
            short8 bre = *reinterpret_cast<const short8*>(sm + WTR + oo * 144 + woff);
            short8 bim = *reinterpret_cast<const short8*>(sm + WTI + oo * 144 + woff);
            yP = MFMA(are, bre, yP); yQ = MFMA(aim, bim, yQ);
            yI = MFMA(are, bim, yI); yI = MFMA(aim, bre, yI);
        }
        #pragma unroll
        for (int r = 0; r < 4; ++r) { yRe[half][r] = yP[r] - yQ[r]; yIm[half][r] = yI[r]; }
    }
    __syncthreads();   // X region dead; reuse as Y-out [comp][b][o] bf16

    #pragma unroll
    for (int half = 0; half < 2; ++half) {
        const int nt = (wv & 1) * 2 + half;
        #pragma unroll
        for (int r = 0; r < 4; ++r) {
            int bb = (lane >> 4) * 4 + r + 16 * mt;
            int o = (lane & 15) + 16 * nt;
            *(ushort_t*)(sm + 0    + bb * 128 + o * 2) = f2bf(yRe[half][r]);
            *(ushort_t*)(sm + 4096 + bb * 128 + o * 2) = f2bf(yIm[half][r]);
        }
    }
    __syncthreads();

    #pragma unroll
    for (int it = 0; it < 2; ++it) {        // coalesced Y store: 8 KB contiguous
        int flat = tid + 256 * it;          // (comp,b,o8) in global order
        short8 v = *reinterpret_cast<const short8*>(sm + flat * 16);
        *reinterpret_cast<short8*>(XY + hu * 4096 + flat * 8) = v;
    }
}

// ---------------------------------------------------------------------------
// K3: per (b, h), TRANSPOSED orientation D[m=channel, n=w].
//   conv: A = conv_w^T (rows o), B = x^T (cols w) — x loaded DIRECTLY from
//         global into per-lane B-fragments (no LDS round-trip).
//   spec (h<32): S = Y.G64inv staged via LDS; then A = S^T (rows c),
//         B = T4 = G128^T (cols w, im pre-negated, 2^-13 folded).
//   Each lane's 4 acc values = 4 consecutive channels -> direct f32x4 stores.
// LDS 28.9 KB -> 3 blocks/CU; h>=32 blocks have a single barrier.
// ---------------------------------------------------------------------------
__global__ __launch_bounds__(512, 6) void k3_inv(
    const float* __restrict__ x, const float* __restrict__ cw, const float* __restrict__ cb,
    const char* __restrict__ tabs, const ushort_t* __restrict__ XY, float* __restrict__ out)
{
    const int b = blockIdx.x, h = blockIdx.y;
    const int tid = threadIdx.x, lane = tid & 63, wv = tid >> 6;
    constexpr int YRE   = 0, YIM = 4608;        // [u32][o64+pad], stride 144B
    constexpr int ST_RE = 9216, ST_IM = 14336;  // S^T [c64][u32+pad], stride 80B
    constexpr int CWT   = 19456;                // conv_w^T [o64][i64+pad], stride 144B
    constexpr int SCB   = 28672;                // bias f32[64]
    __shared__ __align__(16) char sm[28928];

    // ---- per-lane x B-fragment loads: col w = lane&15 + 16*wv, k = i ----
    const float* xs = x + ((size_t)(b * NHt + h)) * (NWd * NC);
    const int ww = (lane & 15) + 16 * wv;
    const float* xrow = xs + ww * 64 + (lane >> 4) * 8;
    f32x4 xa[4];
    #pragma unroll
    for (int ks = 0; ks < 2; ++ks) {
        xa[2*ks]   = __builtin_nontemporal_load(reinterpret_cast<const f32x4*>(xrow + 32 * ks));
        xa[2*ks+1] = __builtin_nontemporal_load(reinterpret_cast<const f32x4*>(xrow + 32 * ks + 4));
    }
    short8 yv = {}, gre = {}, gim = {};
    if (h < MX) {
        int u = tid >> 4, comp = (tid >> 3) & 1, o8 = (tid & 7) * 8;
        size_t hu = (size_t)(h * 32 + u);
        yv = *reinterpret_cast<const short8*>(XY + ((hu * 2 + comp) * 32 + b) * 64 + o8);
        const char* t4 = tabs + TAB_T4 + ((wv * 64 + lane) * 32);
        gre = *reinterpret_cast<const short8*>(t4);
        gim = *reinterpret_cast<const short8*>(t4 + 16);   // already negated
    }

    // ---- stage conv_w^T + bias (+ Y for spec rows) ----
    #pragma unroll
    for (int i = 0; i < 2; ++i) {
        int ii = (tid >> 4) + 32 * i;
        #pragma unroll
        for (int j = 0; j < 4; ++j) {
            int o = (tid & 15) + 16 * j;
            *(ushort_t*)(sm + CWT + o * 144 + ii * 2) = f2bf(cw[ii * 64 + o]);
        }
    }
    if (tid < 64) ((float*)(sm + SCB))[tid] = cb[tid];

    // convert x to bf16 B-fragments while loads drain
    short8 xb[2];
    #pragma unroll
    for (int ks = 0; ks < 2; ++ks) {
        short8 t;
        #pragma unroll
        for (int j = 0; j < 4; ++j) {
            t[j]     = (short)f2bf(xa[2*ks][j]);
            t[4 + j] = (short)f2bf(xa[2*ks+1][j]);
        }
        xb[ks] = t;
    }
    if (h < MX) {
        int u = tid >> 4, comp = (tid >> 3) & 1, o8 = (tid & 7) * 8;
        *reinterpret_cast<short8*>(sm + (comp ? YIM : YRE) + u * 144 + o8 * 2) = yv;
    }
    __syncthreads();

    if (h < MX) {
        // stage 4: S[u,c] = sum_o Y[u,o] G64inv[o,c]; write S transposed [c][u]
        const int mt = wv >> 2, nt = wv & 3;
        f32x4 sP = {0.f,0.f,0.f,0.f}, sQ = {0.f,0.f,0.f,0.f}, sI = {0.f,0.f,0.f,0.f};
        #pragma unroll
        for (int ks = 0; ks < 2; ++ks) {
            short8 are = *reinterpret_cast<const short8*>(
                sm + YRE + ((lane & 15) + 16 * mt) * 144 + (lane >> 4) * 16 + 64 * ks);
            short8 aim = *reinterpret_cast<const short8*>(
                sm + YIM + ((lane & 15) + 16 * mt) * 144 + (lane >> 4) * 16 + 64 * ks);
            const char* t3 = tabs + TAB_T3 + (((nt * 2 + ks) * 64 + lane) * 32);
            short8 bre = *reinterpret_cast<const short8*>(t3);
            short8 bim = *reinterpret_cast<const short8*>(t3 + 16);
            sP = MFMA(are, bre, sP); sQ = MFMA(aim, bim, sQ);
            sI = MFMA(are, bim, sI); sI = MFMA(aim, bre, sI);
        }
        #pragma unroll
        for (int r = 0; r < 4; ++r) {
            int u = (lane >> 4) * 4 + r + 16 * mt;
            int c = (lane & 15) + 16 * nt;
            *(ushort_t*)(sm + ST_RE + c * 80 + u * 2) = f2bf(sP[r] - sQ[r]);
            *(ushort_t*)(sm + ST_IM + c * 80 + u * 2) = f2bf(sI[r]);
        }
        __syncthreads();
    }

    // ---- conv (+spec) MFMAs; direct f32x4 stores (4 consecutive channels) ----
    float* orow = out + ((size_t)(b * NHt + h)) * (NWd * NC);
    #pragma unroll
    for (int mt = 0; mt < 4; ++mt) {
        f32x4 acc = {0.f,0.f,0.f,0.f};
        #pragma unroll
        for (int ks = 0; ks < 2; ++ks) {
            short8 aw = *reinterpret_cast<const short8*>(
                sm + CWT + ((lane & 15) + 16 * mt) * 144 + (lane >> 4) * 16 + 64 * ks);
            acc = MFMA(aw, xb[ks], acc);
        }
        if (h < MX) {
            short8 sre = *reinterpret_cast<const short8*>(
                sm + ST_RE + ((lane & 15) + 16 * mt) * 80 + (lane >> 4) * 16);
            short8 sim = *reinterpret_cast<const short8*>(
                sm + ST_IM + ((lane & 15) + 16 * mt) * 80 + (lane >> 4) * 16);
            acc = MFMA(sre, gre, acc);   // + S_re . G_re
            acc = MFMA(sim, gim, acc);   // + S_im . (-G_im)
        }
        int obase = (lane >> 4) * 4 + 16 * mt;
        f32x4 bias = *reinterpret_cast<const f32x4*>(sm + SCB + obase * 4);
        f32x4 v;
        #pragma unroll
        for (int r = 0; r < 4; ++r) v[r] = fmaxf(acc[r] + bias[r], 0.0f);
        __builtin_nontemporal_store(v, reinterpret_cast<f32x4*>(orow + ww * 64 + obase));
    }
}

extern "C" void kernel_launch(void* const* d_in, const int* in_sizes, int n_in,
                              void* d_out, int out_size, void* d_ws, size_t ws_size,
                              hipStream_t stream) {
    const float* x      = (const float*)d_in[0];
    const float* w_real = (const float*)d_in[1];
    const float* w_imag = (const float*)d_in[2];
    const float* conv_w = (const float*)d_in[3];
    const float* conv_b = (const float*)d_in[4];
    float* out = (float*)d_out;

    char* tabs   = (char*)d_ws;
    ushort_t* XY = (ushort_t*)((char*)d_ws + XY_OFF);

    k1_fwd<<<dim3(NB, MX), 512, 0, stream>>>(x, tabs, XY);
    k2_mix<<<dim3(MX, 32), 256, 0, stream>>>(w_real, w_imag, XY);
    k3_inv<<<dim3(NB, NHt), 512, 0, stream>>>(x, conv_w, conv_b,
                                              (const char*)tabs, XY, out);
}

// Round 8
// 76.759 us; speedup vs baseline: 1.2372x; 1.2372x over previous
//
#include <hip/hip_runtime.h>

typedef __attribute__((ext_vector_type(8))) short short8;
typedef __attribute__((ext_vector_type(4))) short bf16x4;
typedef __attribute__((ext_vector_type(4))) float f32x4;
typedef unsigned short ushort_t;

#define MFMA(a, b, c) __builtin_amdgcn_mfma_f32_16x16x32_bf16((a), (b), (c), 0, 0, 0)

constexpr int NB = 32, NHt = 128, NWd = 128, NC = 64, MX = 32;
constexpr float TWO_PI = 6.28318530717958647692f;

// workspace layout (64 KB tables + 8 MiB X/Y buffer)
constexpr size_t TAB_T3 = 32768;  // spec stage4 B: G64 inv [nt4][ks2][lane64][re8,im8]
constexpr size_t TAB_T4 = 49152;  // spec stage5 A: G128 inv [mt8][lane64][re8,im8] (x 2^-13)
constexpr size_t XY_OFF = 65536;  // X then Y in-place: bf16 [h32][u32][comp2][b32][k64]

__device__ inline ushort_t f2bf(float f) {
    union { float f; unsigned int u; } v; v.f = f;
    unsigned int r = v.u + 0x7FFFu + ((v.u >> 16) & 1u);   // RTN-even
    return (ushort_t)(r >> 16);
}
// row-dependent XOR swizzle (bits 4-5), 16B-granular.
__device__ inline int sxor(int row) { return ((row >> 3) & 3) << 4; }

// ---------------------------------------------------------------------------
// K_A: per (b, h<32). M1 = F128trunc . x, X = M1 . G64fwd. Twiddles inline;
// lead block emits the spec kernel's T3/T4 tables into the workspace.
// ---------------------------------------------------------------------------
__global__ __launch_bounds__(512) void k1_fwd(
    const float* __restrict__ x, char* __restrict__ tabs, ushort_t* __restrict__ XY)
{
    const int b = blockIdx.x, h = blockIdx.y;
    const int tid = threadIdx.x, lane = tid & 63, wv = tid >> 6;
    constexpr int SXT  = 0;            // x^T bf16 [c64][w128], stride 272B; reused for X-out
    constexpr int M1RE = 17408;        // [u32][c64+pad], stride 144B
    constexpr int M1IM = 17408 + 4608;
    __shared__ __align__(16) char sm[26624];

    if (b == 0 && h == 0) {
        {   // T3: G64 inv exp(+2pi i o c/64); entry = tid
            int nt2 = tid >> 7, ks2 = (tid >> 6) & 1, l = tid & 63;
            int cc2 = (l & 15) + 16 * nt2, ob = (l >> 4) * 8 + 32 * ks2;
            short8 vre, vim;
            #pragma unroll
            for (int j = 0; j < 8; ++j) {
                float a = (float)(((ob + j) * cc2) & 63) * (TWO_PI / 64.f);
                float s, c; __sincosf(a, &s, &c);
                vre[j] = (short)f2bf(c); vim[j] = (short)f2bf(s);
            }
            *reinterpret_cast<short8*>(tabs + TAB_T3 + tid * 32)      = vre;
            *reinterpret_cast<short8*>(tabs + TAB_T3 + tid * 32 + 16) = vim;
        }
        {   // T4: G128 inv exp(+2pi i w u/128) * 2^-13; entry = tid
            int mt2 = tid >> 6, l = tid & 63;
            int w = (l & 15) + 16 * mt2, ub = (l >> 4) * 8;
            short8 vre, vim;
            #pragma unroll
            for (int j = 0; j < 8; ++j) {
                float a = (float)((w * (ub + j)) & 127) * (TWO_PI / 128.f);
                float s, c; __sincosf(a, &s, &c);
                vre[j] = (short)f2bf(c * 0.0001220703125f);  // exact 2^-13
                vim[j] = (short)f2bf(s * 0.0001220703125f);
            }
            *reinterpret_cast<short8*>(tabs + TAB_T4 + tid * 32)      = vre;
            *reinterpret_cast<short8*>(tabs + TAB_T4 + tid * 32 + 16) = vim;
        }
    }

    // load x slice (float4) + transpose -> sxT[c][w] bf16 (swizzled)
    const float* xs = x + ((size_t)(b * NHt + h)) * (NWd * NC);
    #pragma unroll
    for (int i = 0; i < 4; ++i) {
        int idx = tid + 512 * i;               // 0..2047 float4s
        int w = idx >> 4, c4 = (idx & 15) * 4;
        f32x4 v = *reinterpret_cast<const f32x4*>(xs + w * 64 + c4);
        #pragma unroll
        for (int j = 0; j < 4; ++j)
            *(ushort_t*)(sm + SXT + (c4 + j) * 272 + ((w * 2) ^ sxor(c4 + j))) = f2bf(v[j]);
    }
    __syncthreads();

    const int mt = wv >> 2, nt = wv & 3;
    // stage 1: M1[u,c] = sum_w F[u,w] x[w,c]; F-frag inline
    f32x4 m1r = {0.f,0.f,0.f,0.f}, m1i = {0.f,0.f,0.f,0.f};
    const int cc = (lane & 15) + 16 * nt;
    const int uu = (lane & 15) + 16 * mt;
    #pragma unroll
    for (int ks = 0; ks < 4; ++ks) {
        short8 bfrag = *reinterpret_cast<const short8*>(
            sm + SXT + cc * 272 + (((lane >> 4) * 16 + 64 * ks) ^ sxor(cc)));
        int wb = (lane >> 4) * 8 + 32 * ks;
        short8 are, aim;
        #pragma unroll
        for (int j = 0; j < 8; ++j) {
            float a = (float)((uu * (wb + j)) & 127) * (TWO_PI / 128.f);
            float s, c; __sincosf(a, &s, &c);
            are[j] = (short)f2bf(c); aim[j] = (short)f2bf(-s);
        }
        m1r = MFMA(are, bfrag, m1r);
        m1i = MFMA(aim, bfrag, m1i);
    }
    #pragma unroll
    for (int r = 0; r < 4; ++r) {
        int u = (lane >> 4) * 4 + r + 16 * mt;
        int c = (lane & 15) + 16 * nt;
        *(ushort_t*)(sm + M1RE + u * 144 + c * 2) = f2bf(m1r[r]);
        *(ushort_t*)(sm + M1IM + u * 144 + c * 2) = f2bf(m1i[r]);
    }
    __syncthreads();

    // stage 2: X[u,k] = sum_c M1[u,c] G64f[c,k]; G-frag inline; out via LDS
    f32x4 xP = {0.f,0.f,0.f,0.f}, xQ = {0.f,0.f,0.f,0.f}, xI = {0.f,0.f,0.f,0.f};
    const int kk = (lane & 15) + 16 * nt;
    #pragma unroll
    for (int ks = 0; ks < 2; ++ks) {
        short8 are = *reinterpret_cast<const short8*>(
            sm + M1RE + ((lane & 15) + 16 * mt) * 144 + (lane >> 4) * 16 + 64 * ks);
        short8 aim = *reinterpret_cast<const short8*>(
            sm + M1IM + ((lane & 15) + 16 * mt) * 144 + (lane >> 4) * 16 + 64 * ks);
        int cb2 = (lane >> 4) * 8 + 32 * ks;
        short8 bre, bim;
        #pragma unroll
        for (int j = 0; j < 8; ++j) {
            float a = (float)((kk * (cb2 + j)) & 63) * (TWO_PI / 64.f);
            float s, c; __sincosf(a, &s, &c);
            bre[j] = (short)f2bf(c); bim[j] = (short)f2bf(-s);
        }
        xP = MFMA(are, bre, xP);
        xQ = MFMA(aim, bim, xQ);
        xI = MFMA(are, bim, xI);
        xI = MFMA(aim, bre, xI);
    }
    #pragma unroll
    for (int r = 0; r < 4; ++r) {
        int u = (lane >> 4) * 4 + r + 16 * mt;
        int k = (lane & 15) + 16 * nt;
        *(ushort_t*)(sm + SXT + 0    + u * 128 + k * 2) = f2bf(xP[r] - xQ[r]);
        *(ushort_t*)(sm + SXT + 4096 + u * 128 + k * 2) = f2bf(xI[r]);
    }
    __syncthreads();

    {   // coalesced X store
        int u = tid >> 4, comp = (tid >> 3) & 1, k8 = (tid & 7) * 8;
        short8 v = *reinterpret_cast<const short8*>(sm + SXT + comp * 4096 + u * 128 + k8 * 2);
        size_t hu = (size_t)(h * 32 + u);
        *reinterpret_cast<short8*>(XY + ((hu * 2 + comp) * 32 + b) * 64 + k8) = v;
    }
}

// ---------------------------------------------------------------------------
// K_B: heterogeneous 256-thread kernel.
//   bid < 1024:  mix-role — Y[b,o] = sum_k X[b,k] W[h,u,k,o] for (h,u).
//   bid >= 1024: conv-role — 1x1 conv + bias + relu for rows h>=32 (64 w per
//                block), independent of the mix output. Overlaps W reads
//                with the x/out stream.
// ---------------------------------------------------------------------------
__global__ __launch_bounds__(256) void k2_fused(
    const float* __restrict__ wre, const float* __restrict__ wim,
    ushort_t* __restrict__ XY,
    const float* __restrict__ x, const float* __restrict__ cw,
    const float* __restrict__ cb, float* __restrict__ out)
{
    const int bid = blockIdx.x;
    const int tid = threadIdx.x, lane = tid & 63, wv = tid >> 6;   // 4 waves
    __shared__ __align__(16) char sm[36096];

    if (bid < 1024) {
        // ================= mix role (= R6 k2_mix) =================
        const int h = bid >> 5, u = bid & 31;
        constexpr int XRE = 0, XIM = 4608, WTR = 9216, WTI = 18432;  // strides 144B
        const size_t hu = (size_t)(h * 32 + u);

        #pragma unroll
        for (int it = 0; it < 2; ++it) {        // stage X[b][k] (both comps)
            int row = (tid >> 3) + 32 * it;
            int comp = row >> 5, bb = row & 31, k8 = (tid & 7) * 8;
            short8 v = *reinterpret_cast<const short8*>(XY + ((hu * 2 + comp) * 32 + bb) * 64 + k8);
            *reinterpret_cast<short8*>(sm + (comp ? XIM : XRE) + bb * 144 + k8 * 2) = v;
        }
        const float* wr = wre + hu * 4096;      // transpose W -> WT[o][k] bf16 (swizzled)
        const float* wi = wim + hu * 4096;
        #pragma unroll
        for (int i = 0; i < 4; ++i) {
            int idx = tid + 256 * i;            // 0..1023
            int k = idx >> 4, o4 = (idx & 15) * 4;
            f32x4 vr = __builtin_nontemporal_load(reinterpret_cast<const f32x4*>(wr + k * 64 + o4));
            f32x4 vi = __builtin_nontemporal_load(reinterpret_cast<const f32x4*>(wi + k * 64 + o4));
            #pragma unroll
            for (int j = 0; j < 4; ++j) {
                int o = o4 + j, koff = (k * 2) ^ sxor(o);
                *(ushort_t*)(sm + WTR + o * 144 + koff) = f2bf(vr[j]);
                *(ushort_t*)(sm + WTI + o * 144 + koff) = f2bf(vi[j]);
            }
        }
        __syncthreads();

        const int mt = wv >> 1;
        f32x4 yRe[2], yIm[2];
        #pragma unroll
        for (int half = 0; half < 2; ++half) {
            const int nt = (wv & 1) * 2 + half;
            const int oo = (lane & 15) + 16 * nt;
            f32x4 yP = {0.f,0.f,0.f,0.f}, yQ = {0.f,0.f,0.f,0.f}, yI = {0.f,0.f,0.f,0.f};
            #pragma unroll
            for (int ks = 0; ks < 2; ++ks) {
                int woff = ((lane >> 4) * 16 + 64 * ks) ^ sxor(oo);
                short8 are = *reinterpret_cast<const short8*>(
                    sm + XRE + ((lane & 15) + 16 * mt) * 144 + (lane >> 4) * 16 + 64 * ks);
                short8 aim = *reinterpret_cast<const short8*>(
                    sm + XIM + ((lane & 15) + 16 * mt) * 144 + (lane >> 4) * 16 + 64 * ks);
                short8 bre = *reinterpret_cast<const short8*>(sm + WTR + oo * 144 + woff);
                short8 bim = *reinterpret_cast<const short8*>(sm + WTI + oo * 144 + woff);
                yP = MFMA(are, bre, yP); yQ = MFMA(aim, bim, yQ);
                yI = MFMA(are, bim, yI); yI = MFMA(aim, bre, yI);
            }
            #pragma unroll
            for (int r = 0; r < 4; ++r) { yRe[half][r] = yP[r] - yQ[r]; yIm[half][r] = yI[r]; }
        }
        __syncthreads();   // X region dead; reuse as Y-out [comp][b][o] bf16

        #pragma unroll
        for (int half = 0; half < 2; ++half) {
            const int nt = (wv & 1) * 2 + half;
            #pragma unroll
            for (int r = 0; r < 4; ++r) {
                int bb = (lane >> 4) * 4 + r + 16 * mt;
                int o = (lane & 15) + 16 * nt;
                *(ushort_t*)(sm + 0    + bb * 128 + o * 2) = f2bf(yRe[half][r]);
                *(ushort_t*)(sm + 4096 + bb * 128 + o * 2) = f2bf(yIm[half][r]);
            }
        }
        __syncthreads();

        #pragma unroll
        for (int it = 0; it < 2; ++it) {        // coalesced Y store
            int flat = tid + 256 * it;
            short8 v = *reinterpret_cast<const short8*>(sm + flat * 16);
            *reinterpret_cast<short8*>(XY + hu * 4096 + flat * 8) = v;
        }
    } else {
        // ================= conv role (h >= 32, 64 w per block) =================
        const int cid = bid - 1024;             // 0..6143
        const int b = cid / 192, rem = cid % 192;
        const int h = MX + (rem >> 1), w0 = (rem & 1) * 64;
        constexpr int XB   = 0;                 // x bf16 [w64][c64+pad], stride 144B
        constexpr int CWT  = 9216;              // conv_w^T [o64][i64+pad], stride 144B
        constexpr int SCB  = 18432;             // bias f32[64]
        constexpr int OUTB = 18688;             // out f32 [w64][c64+4pad], stride 272B

        const float* xs = x + (((size_t)(b * NHt + h)) * NWd + w0) * NC;
        #pragma unroll
        for (int i = 0; i < 4; ++i) {
            int idx = tid + 256 * i;            // 0..1023 float4s
            int w = idx >> 4, c4 = (idx & 15) * 4;
            f32x4 v = *reinterpret_cast<const f32x4*>(xs + w * 64 + c4);
            bf16x4 pk = { (short)f2bf(v[0]), (short)f2bf(v[1]),
                          (short)f2bf(v[2]), (short)f2bf(v[3]) };
            *reinterpret_cast<bf16x4*>(sm + XB + w * 144 + c4 * 2) = pk;
        }
        #pragma unroll
        for (int i = 0; i < 4; ++i) {
            int ii = (tid >> 4) + 16 * i;       // 0..63
            #pragma unroll
            for (int j = 0; j < 4; ++j) {
                int o = (tid & 15) + 16 * j;
                *(ushort_t*)(sm + CWT + o * 144 + ii * 2) = f2bf(cw[ii * 64 + o]);
            }
        }
        if (tid < 64) ((float*)(sm + SCB))[tid] = cb[tid];
        __syncthreads();

        #pragma unroll
        for (int nt = 0; nt < 4; ++nt) {
            f32x4 acc = {0.f,0.f,0.f,0.f};
            #pragma unroll
            for (int ks = 0; ks < 2; ++ks) {
                short8 ah = *reinterpret_cast<const short8*>(
                    sm + XB + ((lane & 15) + 16 * wv) * 144 + (lane >> 4) * 16 + 64 * ks);
                short8 bw = *reinterpret_cast<const short8*>(
                    sm + CWT + ((lane & 15) + 16 * nt) * 144 + (lane >> 4) * 16 + 64 * ks);
                acc = MFMA(ah, bw, acc);
            }
            #pragma unroll
            for (int r = 0; r < 4; ++r) {
                int w = (lane >> 4) * 4 + r + 16 * wv;
                int c = (lane & 15) + 16 * nt;
                float v = acc[r] + ((const float*)(sm + SCB))[c];
                *(float*)(sm + OUTB + w * 272 + c * 4) = fmaxf(v, 0.0f);
            }
        }
        __syncthreads();

        float* orow = out + (((size_t)(b * NHt + h)) * NWd + w0) * NC;
        #pragma unroll
        for (int i = 0; i < 4; ++i) {
            int flat = tid + 256 * i;           // 0..1023 float4s
            int w = flat >> 4, c4 = (flat & 15) * 4;
            f32x4 v = *reinterpret_cast<const f32x4*>(sm + OUTB + w * 272 + c4 * 4);
            __builtin_nontemporal_store(v, reinterpret_cast<f32x4*>(orow + w * 64 + c4));
        }
    }
}

// ---------------------------------------------------------------------------
// K_C (h<32): S = Y.G64inv, spec = Re(G128inv.S) (2^-13 in table) + conv +
// bias + relu. R4/R6 proven structure.
// ---------------------------------------------------------------------------
__global__ __launch_bounds__(512, 4) void k3_spec(
    const float* __restrict__ x, const float* __restrict__ cw, const float* __restrict__ cb,
    const char* __restrict__ tabs, const ushort_t* __restrict__ XY, float* __restrict__ out)
{
    const int b = blockIdx.x, h = blockIdx.y;   // h < 32
    const int tid = threadIdx.x, lane = tid & 63, wv = tid >> 6;
    constexpr int ST_RE = 0, ST_IM = 5120;   // S^T [c64][u32+pad], stride 80B
    constexpr int XB   = 10240;              // x bf16 [w128][c64+pad], stride 144B
    constexpr int CWT  = 28672;              // conv_w^T [o64][i64+pad], stride 144B
    constexpr int SCB  = 37888;              // bias f32[64]
    constexpr int OUTB = 38144;              // out f32 [w128][c64+4pad], stride 272B
    constexpr int YRE  = 38144;              // Y staging inside OUTB (dead by store time)
    constexpr int YIM  = 38144 + 4608;       // strides 144B
    __shared__ __align__(16) char sm[72960];

    // ---- issue all global loads up front ----
    const float* xs = x + ((size_t)(b * NHt + h)) * (NWd * NC);
    f32x4 xv[4];
    #pragma unroll
    for (int i = 0; i < 4; ++i) {
        int idx = tid + 512 * i;
        int w = idx >> 4, c4 = (idx & 15) * 4;
        xv[i] = __builtin_nontemporal_load(reinterpret_cast<const f32x4*>(xs + w * 64 + c4));
    }
    short8 yv, gre, gim;
    {
        int u = tid >> 4, comp = (tid >> 3) & 1, o8 = (tid & 7) * 8;
        size_t hu = (size_t)(h * 32 + u);
        yv = *reinterpret_cast<const short8*>(XY + ((hu * 2 + comp) * 32 + b) * 64 + o8);
        const char* t4 = tabs + TAB_T4 + ((wv * 64 + lane) * 32);
        gre = *reinterpret_cast<const short8*>(t4);
        gim = *reinterpret_cast<const short8*>(t4 + 16);
    }

    // ---- stage x (bf16), conv_w^T, bias, Y ----
    #pragma unroll
    for (int i = 0; i < 4; ++i) {
        int idx = tid + 512 * i;
        int w = idx >> 4, c4 = (idx & 15) * 4;
        bf16x4 pk = { (short)f2bf(xv[i][0]), (short)f2bf(xv[i][1]),
                      (short)f2bf(xv[i][2]), (short)f2bf(xv[i][3]) };
        *reinterpret_cast<bf16x4*>(sm + XB + w * 144 + c4 * 2) = pk;
    }
    #pragma unroll
    for (int i = 0; i < 2; ++i) {
        int ii = (tid >> 4) + 32 * i;
        #pragma unroll
        for (int j = 0; j < 4; ++j) {
            int o = (tid & 15) + 16 * j;
            *(ushort_t*)(sm + CWT + o * 144 + ii * 2) = f2bf(cw[ii * 64 + o]);
        }
    }
    if (tid < 64) ((float*)(sm + SCB))[tid] = cb[tid];
    {
        int u = tid >> 4, comp = (tid >> 3) & 1, o8 = (tid & 7) * 8;
        *reinterpret_cast<short8*>(sm + (comp ? YIM : YRE) + u * 144 + o8 * 2) = yv;
    }
    __syncthreads();

    // stage 4: S[u,c] = sum_o Y[u,o] G64inv[o,c]; write S transposed [c][u]
    {
        const int mt = wv >> 2, nt = wv & 3;
        f32x4 sP = {0.f,0.f,0.f,0.f}, sQ = {0.f,0.f,0.f,0.f}, sI = {0.f,0.f,0.f,0.f};
        #pragma unroll
        for (int ks = 0; ks < 2; ++ks) {
            short8 are = *reinterpret_cast<const short8*>(
                sm + YRE + ((lane & 15) + 16 * mt) * 144 + (lane >> 4) * 16 + 64 * ks);
            short8 aim = *reinterpret_cast<const short8*>(
                sm + YIM + ((lane & 15) + 16 * mt) * 144 + (lane >> 4) * 16 + 64 * ks);
            const char* t3 = tabs + TAB_T3 + (((nt * 2 + ks) * 64 + lane) * 32);
            short8 bre = *reinterpret_cast<const short8*>(t3);
            short8 bim = *reinterpret_cast<const short8*>(t3 + 16);
            sP = MFMA(are, bre, sP); sQ = MFMA(aim, bim, sQ);
            sI = MFMA(are, bim, sI); sI = MFMA(aim, bre, sI);
        }
        #pragma unroll
        for (int r = 0; r < 4; ++r) {
            int u = (lane >> 4) * 4 + r + 16 * mt;
            int c = (lane & 15) + 16 * nt;
            *(ushort_t*)(sm + ST_RE + c * 80 + u * 2) = f2bf(sP[r] - sQ[r]);
            *(ushort_t*)(sm + ST_IM + c * 80 + u * 2) = f2bf(sI[r]);
        }
    }
    __syncthreads();

    // ---- conv + spec MFMAs; stream results into padded LDS out buffer ----
    #pragma unroll
    for (int nt = 0; nt < 4; ++nt) {
        f32x4 acc = {0.f,0.f,0.f,0.f};
        #pragma unroll
        for (int ks = 0; ks < 2; ++ks) {
            short8 ah = *reinterpret_cast<const short8*>(
                sm + XB + ((lane & 15) + 16 * wv) * 144 + (lane >> 4) * 16 + 64 * ks);
            short8 bw = *reinterpret_cast<const short8*>(
                sm + CWT + ((lane & 15) + 16 * nt) * 144 + (lane >> 4) * 16 + 64 * ks);
            acc = MFMA(ah, bw, acc);
        }
        short8 bre = *reinterpret_cast<const short8*>(
            sm + ST_RE + ((lane & 15) + 16 * nt) * 80 + (lane >> 4) * 16);
        short8 bim = *reinterpret_cast<const short8*>(
            sm + ST_IM + ((lane & 15) + 16 * nt) * 80 + (lane >> 4) * 16);
        f32x4 sp = {0.f,0.f,0.f,0.f}, sq = {0.f,0.f,0.f,0.f};
        sp = MFMA(gre, bre, sp);
        sq = MFMA(gim, bim, sq);
        #pragma unroll
        for (int r = 0; r < 4; ++r) {
            int w = (lane >> 4) * 4 + r + 16 * wv;
            int c = (lane & 15) + 16 * nt;
            float v = acc[r] + ((const float*)(sm + SCB))[c] + sp[r] - sq[r];
            *(float*)(sm + OUTB + w * 272 + c * 4) = fmaxf(v, 0.0f);
        }
    }
    __syncthreads();

    // ---- fully coalesced nontemporal stores ----
    float* orow = out + ((size_t)(b * NHt + h)) * (NWd * NC);
    #pragma unroll
    for (int i = 0; i < 4; ++i) {
        int flat = tid + 512 * i;
        int w = flat >> 4, c4 = (flat & 15) * 4;
        f32x4 v = *reinterpret_cast<const f32x4*>(sm + OUTB + w * 272 + c4 * 4);
        __builtin_nontemporal_store(v, reinterpret_cast<f32x4*>(orow + w * 64 + c4));
    }
}

extern "C" void kernel_launch(void* const* d_in, const int* in_sizes, int n_in,
                              void* d_out, int out_size, void* d_ws, size_t ws_size,
                              hipStream_t stream) {
    const float* x      = (const float*)d_in[0];
    const float* w_real = (const float*)d_in[1];
    const float* w_imag = (const float*)d_in[2];
    const float* conv_w = (const float*)d_in[3];
    const float* conv_b = (const float*)d_in[4];
    float* out = (float*)d_out;

    char* tabs   = (char*)d_ws;
    ushort_t* XY = (ushort_t*)((char*)d_ws + XY_OFF);

    k1_fwd<<<dim3(NB, MX), 512, 0, stream>>>(x, tabs, XY);
    k2_fused<<<1024 + NB * (NHt - MX) * 2, 256, 0, stream>>>(
        w_real, w_imag, XY, x, conv_w, conv_b, out);
    k3_spec<<<dim3(NB, MX), 512, 0, stream>>>(x, conv_w, conv_b,
                                              (const char*)tabs, XY, out);
}

// Round 9
// 73.291 us; speedup vs baseline: 1.2958x; 1.0473x over previous
//
#include <hip/hip_runtime.h>

typedef __attribute__((ext_vector_type(8))) short short8;
typedef __attribute__((ext_vector_type(4))) short bf16x4;
typedef __attribute__((ext_vector_type(4))) float f32x4;
typedef unsigned short ushort_t;

#define MFMA(a, b, c) __builtin_amdgcn_mfma_f32_16x16x32_bf16((a), (b), (c), 0, 0, 0)

constexpr int NB = 32, NHt = 128, NWd = 128, NC = 64, MX = 32;
constexpr float TWO_PI = 6.28318530717958647692f;

// workspace layout (64 KB tables + 8 MiB X/Y buffer)
constexpr size_t TAB_T3 = 32768;  // spec stage4 B: G64 inv [nt4][ks2][lane64][re8,im8]
constexpr size_t TAB_T4 = 49152;  // spec stage5 A: G128 inv [mt8][lane64][re8,im8] (x 2^-13)
constexpr size_t XY_OFF = 65536;  // X then Y in-place: bf16 [h32][u32][comp2][b32][k64]

// conv-row (h>=32) linear index r in [0,3072): b = r/96, h = 32 + r%96.
// L1 covers r [0,512) as quarter-rows; L2 [512,2048) as half-rows;
// L3 [2048,3072) as full rows.

__device__ inline ushort_t f2bf(float f) {
    union { float f; unsigned int u; } v; v.f = f;
    unsigned int r = v.u + 0x7FFFu + ((v.u >> 16) & 1u);   // RTN-even
    return (ushort_t)(r >> 16);
}
// row-dependent XOR swizzle (bits 4-5), 16B-granular.
__device__ inline int sxor(int row) { return ((row >> 3) & 3) << 4; }

// ---------------------------------------------------------------------------
// L1 (512t): bid<1024 -> k1-role: per (b,h<32) M1 = F128trunc.x, X = M1.G64f;
//            twiddles inline; lead block emits T3/T4 tables.
//            bid>=1024 -> quarter-row conv (32 w), LDS 22.8 KB < k1's 26.6 KB.
// ---------------------------------------------------------------------------
__global__ __launch_bounds__(512) void k1_fused(
    const float* __restrict__ x, char* __restrict__ tabs, ushort_t* __restrict__ XY,
    const float* __restrict__ cw, const float* __restrict__ cb, float* __restrict__ out)
{
    const int bid = blockIdx.x;
    const int tid = threadIdx.x, lane = tid & 63, wv = tid >> 6;
    __shared__ __align__(16) char sm[26624];

    if (bid < 1024) {
        const int b = bid & 31, h = bid >> 5;
        constexpr int SXT  = 0;            // x^T bf16 [c64][w128], stride 272B; reused for X-out
        constexpr int M1RE = 17408;        // [u32][c64+pad], stride 144B
        constexpr int M1IM = 17408 + 4608;

        if (bid == 0) {
            {   // T3: G64 inv exp(+2pi i o c/64); entry = tid
                int nt2 = tid >> 7, ks2 = (tid >> 6) & 1, l = tid & 63;
                int cc2 = (l & 15) + 16 * nt2, ob = (l >> 4) * 8 + 32 * ks2;
                short8 vre, vim;
                #pragma unroll
                for (int j = 0; j < 8; ++j) {
                    float a = (float)(((ob + j) * cc2) & 63) * (TWO_PI / 64.f);
                    float s, c; __sincosf(a, &s, &c);
                    vre[j] = (short)f2bf(c); vim[j] = (short)f2bf(s);
                }
                *reinterpret_cast<short8*>(tabs + TAB_T3 + tid * 32)      = vre;
                *reinterpret_cast<short8*>(tabs + TAB_T3 + tid * 32 + 16) = vim;
            }
            {   // T4: G128 inv exp(+2pi i w u/128) * 2^-13; entry = tid
                int mt2 = tid >> 6, l = tid & 63;
                int w = (l & 15) + 16 * mt2, ub = (l >> 4) * 8;
                short8 vre, vim;
                #pragma unroll
                for (int j = 0; j < 8; ++j) {
                    float a = (float)((w * (ub + j)) & 127) * (TWO_PI / 128.f);
                    float s, c; __sincosf(a, &s, &c);
                    vre[j] = (short)f2bf(c * 0.0001220703125f);  // exact 2^-13
                    vim[j] = (short)f2bf(s * 0.0001220703125f);
                }
                *reinterpret_cast<short8*>(tabs + TAB_T4 + tid * 32)      = vre;
                *reinterpret_cast<short8*>(tabs + TAB_T4 + tid * 32 + 16) = vim;
            }
        }

        // load x slice + transpose -> sxT[c][w] bf16 (swizzled)
        const float* xs = x + ((size_t)(b * NHt + h)) * (NWd * NC);
        #pragma unroll
        for (int i = 0; i < 4; ++i) {
            int idx = tid + 512 * i;               // 0..2047 float4s
            int w = idx >> 4, c4 = (idx & 15) * 4;
            f32x4 v = *reinterpret_cast<const f32x4*>(xs + w * 64 + c4);
            #pragma unroll
            for (int j = 0; j < 4; ++j)
                *(ushort_t*)(sm + SXT + (c4 + j) * 272 + ((w * 2) ^ sxor(c4 + j))) = f2bf(v[j]);
        }
        __syncthreads();

        const int mt = wv >> 2, nt = wv & 3;
        // stage 1: M1[u,c] = sum_w F[u,w] x[w,c]; F-frag inline
        f32x4 m1r = {0.f,0.f,0.f,0.f}, m1i = {0.f,0.f,0.f,0.f};
        const int cc = (lane & 15) + 16 * nt;
        const int uu = (lane & 15) + 16 * mt;
        #pragma unroll
        for (int ks = 0; ks < 4; ++ks) {
            short8 bfrag = *reinterpret_cast<const short8*>(
                sm + SXT + cc * 272 + (((lane >> 4) * 16 + 64 * ks) ^ sxor(cc)));
            int wb = (lane >> 4) * 8 + 32 * ks;
            short8 are, aim;
            #pragma unroll
            for (int j = 0; j < 8; ++j) {
                float a = (float)((uu * (wb + j)) & 127) * (TWO_PI / 128.f);
                float s, c; __sincosf(a, &s, &c);
                are[j] = (short)f2bf(c); aim[j] = (short)f2bf(-s);
            }
            m1r = MFMA(are, bfrag, m1r);
            m1i = MFMA(aim, bfrag, m1i);
        }
        #pragma unroll
        for (int r = 0; r < 4; ++r) {
            int u = (lane >> 4) * 4 + r + 16 * mt;
            int c = (lane & 15) + 16 * nt;
            *(ushort_t*)(sm + M1RE + u * 144 + c * 2) = f2bf(m1r[r]);
            *(ushort_t*)(sm + M1IM + u * 144 + c * 2) = f2bf(m1i[r]);
        }
        __syncthreads();

        // stage 2: X[u,k] = sum_c M1[u,c] G64f[c,k]; G-frag inline
        f32x4 xP = {0.f,0.f,0.f,0.f}, xQ = {0.f,0.f,0.f,0.f}, xI = {0.f,0.f,0.f,0.f};
        const int kk = (lane & 15) + 16 * nt;
        #pragma unroll
        for (int ks = 0; ks < 2; ++ks) {
            short8 are = *reinterpret_cast<const short8*>(
                sm + M1RE + ((lane & 15) + 16 * mt) * 144 + (lane >> 4) * 16 + 64 * ks);
            short8 aim = *reinterpret_cast<const short8*>(
                sm + M1IM + ((lane & 15) + 16 * mt) * 144 + (lane >> 4) * 16 + 64 * ks);
            int cb2 = (lane >> 4) * 8 + 32 * ks;
            short8 bre, bim;
            #pragma unroll
            for (int j = 0; j < 8; ++j) {
                float a = (float)((kk * (cb2 + j)) & 63) * (TWO_PI / 64.f);
                float s, c; __sincosf(a, &s, &c);
                bre[j] = (short)f2bf(c); bim[j] = (short)f2bf(-s);
            }
            xP = MFMA(are, bre, xP);
            xQ = MFMA(aim, bim, xQ);
            xI = MFMA(are, bim, xI);
            xI = MFMA(aim, bre, xI);
        }
        #pragma unroll
        for (int r = 0; r < 4; ++r) {
            int u = (lane >> 4) * 4 + r + 16 * mt;
            int k = (lane & 15) + 16 * nt;
            *(ushort_t*)(sm + SXT + 0    + u * 128 + k * 2) = f2bf(xP[r] - xQ[r]);
            *(ushort_t*)(sm + SXT + 4096 + u * 128 + k * 2) = f2bf(xI[r]);
        }
        __syncthreads();

        {   // coalesced X store
            int u = tid >> 4, comp = (tid >> 3) & 1, k8 = (tid & 7) * 8;
            short8 v = *reinterpret_cast<const short8*>(sm + SXT + comp * 4096 + u * 128 + k8 * 2);
            size_t hu = (size_t)(h * 32 + u);
            *reinterpret_cast<short8*>(XY + ((hu * 2 + comp) * 32 + b) * 64 + k8) = v;
        }
    } else {
        // ============ quarter-row conv (32 w), rows r in [0,512) ============
        const int qid = bid - 1024;             // 0..2047
        const int r = qid >> 2;
        const int b = r / 96, h = MX + r % 96, w0 = (qid & 3) * 32;
        constexpr int XB   = 0;                 // x bf16 [w32][c64+pad], stride 144B
        constexpr int CWT  = 4608;              // conv_w^T [o64][i64+pad], stride 144B
        constexpr int SCB  = 13824;             // bias f32[64]
        constexpr int OUTB = 14080;             // out f32 [w32][c64+4pad], stride 272B

        const float* xs = x + (((size_t)(b * NHt + h)) * NWd + w0) * NC;
        {
            int w = tid >> 4, c4 = (tid & 15) * 4;
            f32x4 v = *reinterpret_cast<const f32x4*>(xs + w * 64 + c4);
            bf16x4 pk = { (short)f2bf(v[0]), (short)f2bf(v[1]),
                          (short)f2bf(v[2]), (short)f2bf(v[3]) };
            *reinterpret_cast<bf16x4*>(sm + XB + w * 144 + c4 * 2) = pk;
        }
        #pragma unroll
        for (int i = 0; i < 2; ++i) {
            int ii = (tid >> 4) + 32 * i;
            #pragma unroll
            for (int j = 0; j < 4; ++j) {
                int o = (tid & 15) + 16 * j;
                *(ushort_t*)(sm + CWT + o * 144 + ii * 2) = f2bf(cw[ii * 64 + o]);
            }
        }
        if (tid < 64) ((float*)(sm + SCB))[tid] = cb[tid];
        __syncthreads();

        const int mt = wv >> 2, nt = wv & 3;    // 2 w-tiles x 4 c-tiles
        f32x4 acc = {0.f,0.f,0.f,0.f};
        #pragma unroll
        for (int ks = 0; ks < 2; ++ks) {
            short8 ah = *reinterpret_cast<const short8*>(
                sm + XB + ((lane & 15) + 16 * mt) * 144 + (lane >> 4) * 16 + 64 * ks);
            short8 bw = *reinterpret_cast<const short8*>(
                sm + CWT + ((lane & 15) + 16 * nt) * 144 + (lane >> 4) * 16 + 64 * ks);
            acc = MFMA(ah, bw, acc);
        }
        #pragma unroll
        for (int r4 = 0; r4 < 4; ++r4) {
            int w = (lane >> 4) * 4 + r4 + 16 * mt;
            int c = (lane & 15) + 16 * nt;
            float v = acc[r4] + ((const float*)(sm + SCB))[c];
            *(float*)(sm + OUTB + w * 272 + c * 4) = fmaxf(v, 0.0f);
        }
        __syncthreads();

        float* orow = out + (((size_t)(b * NHt + h)) * NWd + w0) * NC;
        {
            int w = tid >> 4, c4 = (tid & 15) * 4;
            f32x4 v = *reinterpret_cast<const f32x4*>(sm + OUTB + w * 272 + c4 * 4);
            __builtin_nontemporal_store(v, reinterpret_cast<f32x4*>(orow + w * 64 + c4));
        }
    }
}

// ---------------------------------------------------------------------------
// L2 (256t): bid<1024 -> mix-role: Y[b,o] = sum_k X[b,k] W[h,u,k,o].
//            bid>=1024 -> half-row conv (64 w), rows r in [512,2048).
// ---------------------------------------------------------------------------
__global__ __launch_bounds__(256) void k2_fused(
    const float* __restrict__ wre, const float* __restrict__ wim,
    ushort_t* __restrict__ XY,
    const float* __restrict__ x, const float* __restrict__ cw,
    const float* __restrict__ cb, float* __restrict__ out)
{
    const int bid = blockIdx.x;
    const int tid = threadIdx.x, lane = tid & 63, wv = tid >> 6;   // 4 waves
    __shared__ __align__(16) char sm[36096];

    if (bid < 1024) {
        const int h = bid >> 5, u = bid & 31;
        constexpr int XRE = 0, XIM = 4608, WTR = 9216, WTI = 18432;  // strides 144B
        const size_t hu = (size_t)(h * 32 + u);

        #pragma unroll
        for (int it = 0; it < 2; ++it) {        // stage X[b][k] (both comps)
            int row = (tid >> 3) + 32 * it;
            int comp = row >> 5, bb = row & 31, k8 = (tid & 7) * 8;
            short8 v = *reinterpret_cast<const short8*>(XY + ((hu * 2 + comp) * 32 + bb) * 64 + k8);
            *reinterpret_cast<short8*>(sm + (comp ? XIM : XRE) + bb * 144 + k8 * 2) = v;
        }
        const float* wr = wre + hu * 4096;      // transpose W -> WT[o][k] bf16 (swizzled)
        const float* wi = wim + hu * 4096;
        #pragma unroll
        for (int i = 0; i < 4; ++i) {
            int idx = tid + 256 * i;            // 0..1023
            int k = idx >> 4, o4 = (idx & 15) * 4;
            f32x4 vr = __builtin_nontemporal_load(reinterpret_cast<const f32x4*>(wr + k * 64 + o4));
            f32x4 vi = __builtin_nontemporal_load(reinterpret_cast<const f32x4*>(wi + k * 64 + o4));
            #pragma unroll
            for (int j = 0; j < 4; ++j) {
                int o = o4 + j, koff = (k * 2) ^ sxor(o);
                *(ushort_t*)(sm + WTR + o * 144 + koff) = f2bf(vr[j]);
                *(ushort_t*)(sm + WTI + o * 144 + koff) = f2bf(vi[j]);
            }
        }
        __syncthreads();

        const int mt = wv >> 1;
        f32x4 yRe[2], yIm[2];
        #pragma unroll
        for (int half = 0; half < 2; ++half) {
            const int nt = (wv & 1) * 2 + half;
            const int oo = (lane & 15) + 16 * nt;
            f32x4 yP = {0.f,0.f,0.f,0.f}, yQ = {0.f,0.f,0.f,0.f}, yI = {0.f,0.f,0.f,0.f};
            #pragma unroll
            for (int ks = 0; ks < 2; ++ks) {
                int woff = ((lane >> 4) * 16 + 64 * ks) ^ sxor(oo);
                short8 are = *reinterpret_cast<const short8*>(
                    sm + XRE + ((lane & 15) + 16 * mt) * 144 + (lane >> 4) * 16 + 64 * ks);
                short8 aim = *reinterpret_cast<const short8*>(
                    sm + XIM + ((lane & 15) + 16 * mt) * 144 + (lane >> 4) * 16 + 64 * ks);
                short8 bre = *reinterpret_cast<const short8*>(sm + WTR + oo * 144 + woff);
                short8 bim = *reinterpret_cast<const short8*>(sm + WTI + oo * 144 + woff);
                yP = MFMA(are, bre, yP); yQ = MFMA(aim, bim, yQ);
                yI = MFMA(are, bim, yI); yI = MFMA(aim, bre, yI);
            }
            #pragma unroll
            for (int r = 0; r < 4; ++r) { yRe[half][r] = yP[r] - yQ[r]; yIm[half][r] = yI[r]; }
        }
        __syncthreads();   // X region dead; reuse as Y-out [comp][b][o] bf16

        #pragma unroll
        for (int half = 0; half < 2; ++half) {
            const int nt = (wv & 1) * 2 + half;
            #pragma unroll
            for (int r = 0; r < 4; ++r) {
                int bb = (lane >> 4) * 4 + r + 16 * mt;
                int o = (lane & 15) + 16 * nt;
                *(ushort_t*)(sm + 0    + bb * 128 + o * 2) = f2bf(yRe[half][r]);
                *(ushort_t*)(sm + 4096 + bb * 128 + o * 2) = f2bf(yIm[half][r]);
            }
        }
        __syncthreads();

        #pragma unroll
        for (int it = 0; it < 2; ++it) {        // coalesced Y store
            int flat = tid + 256 * it;
            short8 v = *reinterpret_cast<const short8*>(sm + flat * 16);
            *reinterpret_cast<short8*>(XY + hu * 4096 + flat * 8) = v;
        }
    } else {
        // ============ half-row conv (64 w), rows r in [512,2048) ============
        const int hid = bid - 1024;             // 0..3071
        const int r = 512 + (hid >> 1);
        const int b = r / 96, h = MX + r % 96, w0 = (hid & 1) * 64;
        constexpr int XB   = 0;                 // x bf16 [w64][c64+pad], stride 144B
        constexpr int CWT  = 9216;              // conv_w^T [o64][i64+pad], stride 144B
        constexpr int SCB  = 18432;             // bias f32[64]
        constexpr int OUTB = 18688;             // out f32 [w64][c64+4pad], stride 272B

        const float* xs = x + (((size_t)(b * NHt + h)) * NWd + w0) * NC;
        #pragma unroll
        for (int i = 0; i < 4; ++i) {
            int idx = tid + 256 * i;            // 0..1023 float4s
            int w = idx >> 4, c4 = (idx & 15) * 4;
            f32x4 v = *reinterpret_cast<const f32x4*>(xs + w * 64 + c4);
            bf16x4 pk = { (short)f2bf(v[0]), (short)f2bf(v[1]),
                          (short)f2bf(v[2]), (short)f2bf(v[3]) };
            *reinterpret_cast<bf16x4*>(sm + XB + w * 144 + c4 * 2) = pk;
        }
        #pragma unroll
        for (int i = 0; i < 4; ++i) {
            int ii = (tid >> 4) + 16 * i;       // 0..63
            #pragma unroll
            for (int j = 0; j < 4; ++j) {
                int o = (tid & 15) + 16 * j;
                *(ushort_t*)(sm + CWT + o * 144 + ii * 2) = f2bf(cw[ii * 64 + o]);
            }
        }
        if (tid < 64) ((float*)(sm + SCB))[tid] = cb[tid];
        __syncthreads();

        #pragma unroll
        for (int nt = 0; nt < 4; ++nt) {
            f32x4 acc = {0.f,0.f,0.f,0.f};
            #pragma unroll
            for (int ks = 0; ks < 2; ++ks) {
                short8 ah = *reinterpret_cast<const short8*>(
                    sm + XB + ((lane & 15) + 16 * wv) * 144 + (lane >> 4) * 16 + 64 * ks);
                short8 bw = *reinterpret_cast<const short8*>(
                    sm + CWT + ((lane & 15) + 16 * nt) * 144 + (lane >> 4) * 16 + 64 * ks);
                acc = MFMA(ah, bw, acc);
            }
            #pragma unroll
            for (int r4 = 0; r4 < 4; ++r4) {
                int w = (lane >> 4) * 4 + r4 + 16 * wv;
                int c = (lane & 15) + 16 * nt;
                float v = acc[r4] + ((const float*)(sm + SCB))[c];
                *(float*)(sm + OUTB + w * 272 + c * 4) = fmaxf(v, 0.0f);
            }
        }
        __syncthreads();

        float* orow = out + (((size_t)(b * NHt + h)) * NWd + w0) * NC;
        #pragma unroll
        for (int i = 0; i < 4; ++i) {
            int flat = tid + 256 * i;
            int w = flat >> 4, c4 = (flat & 15) * 4;
            f32x4 v = *reinterpret_cast<const f32x4*>(sm + OUTB + w * 272 + c4 * 4);
            __builtin_nontemporal_store(v, reinterpret_cast<f32x4*>(orow + w * 64 + c4));
        }
    }
}

// ---------------------------------------------------------------------------
// L3 (512t): bid<1024 -> spec-role (h<32): S = Y.G64inv, spec = Re(G128inv.S)
//            + conv + bias + relu.
//            bid>=1024 -> full-row conv (128 w), rows r in [2048,3072).
//            Conv union 62.7 KB < spec's 73 KB.
// ---------------------------------------------------------------------------
__global__ __launch_bounds__(512, 4) void k3_fused(
    const float* __restrict__ x, const float* __restrict__ cw, const float* __restrict__ cb,
    const char* __restrict__ tabs, const ushort_t* __restrict__ XY, float* __restrict__ out)
{
    const int bid = blockIdx.x;
    const int tid = threadIdx.x, lane = tid & 63, wv = tid >> 6;
    __shared__ __align__(16) char sm[72960];

    if (bid < 1024) {
        const int b = bid & 31, h = bid >> 5;   // h < 32
        constexpr int ST_RE = 0, ST_IM = 5120;  // S^T [c64][u32+pad], stride 80B
        constexpr int XB   = 10240;             // x bf16 [w128][c64+pad], stride 144B
        constexpr int CWT  = 28672;             // conv_w^T [o64][i64+pad], stride 144B
        constexpr int SCB  = 37888;             // bias f32[64]
        constexpr int OUTB = 38144;             // out f32 [w128][c64+4pad], stride 272B
        constexpr int YRE  = 38144;             // Y staging inside OUTB (dead by store time)
        constexpr int YIM  = 38144 + 4608;      // strides 144B

        // ---- issue all global loads up front ----
        const float* xs = x + ((size_t)(b * NHt + h)) * (NWd * NC);
        f32x4 xv[4];
        #pragma unroll
        for (int i = 0; i < 4; ++i) {
            int idx = tid + 512 * i;
            int w = idx >> 4, c4 = (idx & 15) * 4;
            xv[i] = __builtin_nontemporal_load(reinterpret_cast<const f32x4*>(xs + w * 64 + c4));
        }
        short8 yv, gre, gim;
        {
            int u = tid >> 4, comp = (tid >> 3) & 1, o8 = (tid & 7) * 8;
            size_t hu = (size_t)(h * 32 + u);
            yv = *reinterpret_cast<const short8*>(XY + ((hu * 2 + comp) * 32 + b) * 64 + o8);
            const char* t4 = tabs + TAB_T4 + ((wv * 64 + lane) * 32);
            gre = *reinterpret_cast<const short8*>(t4);
            gim = *reinterpret_cast<const short8*>(t4 + 16);
        }

        // ---- stage x (bf16), conv_w^T, bias, Y ----
        #pragma unroll
        for (int i = 0; i < 4; ++i) {
            int idx = tid + 512 * i;
            int w = idx >> 4, c4 = (idx & 15) * 4;
            bf16x4 pk = { (short)f2bf(xv[i][0]), (short)f2bf(xv[i][1]),
                          (short)f2bf(xv[i][2]), (short)f2bf(xv[i][3]) };
            *reinterpret_cast<bf16x4*>(sm + XB + w * 144 + c4 * 2) = pk;
        }
        #pragma unroll
        for (int i = 0; i < 2; ++i) {
            int ii = (tid >> 4) + 32 * i;
            #pragma unroll
            for (int j = 0; j < 4; ++j) {
                int o = (tid & 15) + 16 * j;
                *(ushort_t*)(sm + CWT + o * 144 + ii * 2) = f2bf(cw[ii * 64 + o]);
            }
        }
        if (tid < 64) ((float*)(sm + SCB))[tid] = cb[tid];
        {
            int u = tid >> 4, comp = (tid >> 3) & 1, o8 = (tid & 7) * 8;
            *reinterpret_cast<short8*>(sm + (comp ? YIM : YRE) + u * 144 + o8 * 2) = yv;
        }
        __syncthreads();

        // stage 4: S[u,c] = sum_o Y[u,o] G64inv[o,c]; write S transposed [c][u]
        {
            const int mt = wv >> 2, nt = wv & 3;
            f32x4 sP = {0.f,0.f,0.f,0.f}, sQ = {0.f,0.f,0.f,0.f}, sI = {0.f,0.f,0.f,0.f};
            #pragma unroll
            for (int ks = 0; ks < 2; ++ks) {
                short8 are = *reinterpret_cast<const short8*>(
                    sm + YRE + ((lane & 15) + 16 * mt) * 144 + (lane >> 4) * 16 + 64 * ks);
                short8 aim = *reinterpret_cast<const short8*>(
                    sm + YIM + ((lane & 15) + 16 * mt) * 144 + (lane >> 4) * 16 + 64 * ks);
                const char* t3 = tabs + TAB_T3 + (((nt * 2 + ks) * 64 + lane) * 32);
                short8 bre = *reinterpret_cast<const short8*>(t3);
                short8 bim = *reinterpret_cast<const short8*>(t3 + 16);
                sP = MFMA(are, bre, sP); sQ = MFMA(aim, bim, sQ);
                sI = MFMA(are, bim, sI); sI = MFMA(aim, bre, sI);
            }
            #pragma unroll
            for (int r = 0; r < 4; ++r) {
                int u = (lane >> 4) * 4 + r + 16 * mt;
                int c = (lane & 15) + 16 * nt;
                *(ushort_t*)(sm + ST_RE + c * 80 + u * 2) = f2bf(sP[r] - sQ[r]);
                *(ushort_t*)(sm + ST_IM + c * 80 + u * 2) = f2bf(sI[r]);
            }
        }
        __syncthreads();

        // ---- conv + spec MFMAs -> padded LDS out buffer ----
        #pragma unroll
        for (int nt = 0; nt < 4; ++nt) {
            f32x4 acc = {0.f,0.f,0.f,0.f};
            #pragma unroll
            for (int ks = 0; ks < 2; ++ks) {
                short8 ah = *reinterpret_cast<const short8*>(
                    sm + XB + ((lane & 15) + 16 * wv) * 144 + (lane >> 4) * 16 + 64 * ks);
                short8 bw = *reinterpret_cast<const short8*>(
                    sm + CWT + ((lane & 15) + 16 * nt) * 144 + (lane >> 4) * 16 + 64 * ks);
                acc = MFMA(ah, bw, acc);
            }
            short8 bre = *reinterpret_cast<const short8*>(
                sm + ST_RE + ((lane & 15) + 16 * nt) * 80 + (lane >> 4) * 16);
            short8 bim = *reinterpret_cast<const short8*>(
                sm + ST_IM + ((lane & 15) + 16 * nt) * 80 + (lane >> 4) * 16);
            f32x4 sp = {0.f,0.f,0.f,0.f}, sq = {0.f,0.f,0.f,0.f};
            sp = MFMA(gre, bre, sp);
            sq = MFMA(gim, bim, sq);
            #pragma unroll
            for (int r = 0; r < 4; ++r) {
                int w = (lane >> 4) * 4 + r + 16 * wv;
                int c = (lane & 15) + 16 * nt;
                float v = acc[r] + ((const float*)(sm + SCB))[c] + sp[r] - sq[r];
                *(float*)(sm + OUTB + w * 272 + c * 4) = fmaxf(v, 0.0f);
            }
        }
        __syncthreads();

        // ---- fully coalesced nontemporal stores ----
        float* orow = out + ((size_t)(b * NHt + h)) * (NWd * NC);
        #pragma unroll
        for (int i = 0; i < 4; ++i) {
            int flat = tid + 512 * i;
            int w = flat >> 4, c4 = (flat & 15) * 4;
            f32x4 v = *reinterpret_cast<const f32x4*>(sm + OUTB + w * 272 + c4 * 4);
            __builtin_nontemporal_store(v, reinterpret_cast<f32x4*>(orow + w * 64 + c4));
        }
    } else {
        // ============ full-row conv (128 w), rows r in [2048,3072) ============
        const int fid = bid - 1024;             // 0..1023
        const int r = 2048 + fid;
        const int b = r / 96, h = MX + r % 96;
        constexpr int XB   = 0;                 // x bf16 [w128][c64+pad], stride 144B
        constexpr int CWT  = 18432;             // conv_w^T [o64][i64+pad], stride 144B
        constexpr int SCB  = 27648;             // bias f32[64]
        constexpr int OUTB = 27904;             // out f32 [w128][c64+4pad], stride 272B

        const float* xs = x + ((size_t)(b * NHt + h)) * (NWd * NC);
        #pragma unroll
        for (int i = 0; i < 4; ++i) {
            int idx = tid + 512 * i;            // 0..2047 float4s
            int w = idx >> 4, c4 = (idx & 15) * 4;
            f32x4 v = *reinterpret_cast<const f32x4*>(xs + w * 64 + c4);
            bf16x4 pk = { (short)f2bf(v[0]), (short)f2bf(v[1]),
                          (short)f2bf(v[2]), (short)f2bf(v[3]) };
            *reinterpret_cast<bf16x4*>(sm + XB + w * 144 + c4 * 2) = pk;
        }
        #pragma unroll
        for (int i = 0; i < 2; ++i) {
            int ii = (tid >> 4) + 32 * i;
            #pragma unroll
            for (int j = 0; j < 4; ++j) {
                int o = (tid & 15) + 16 * j;
                *(ushort_t*)(sm + CWT + o * 144 + ii * 2) = f2bf(cw[ii * 64 + o]);
            }
        }
        if (tid < 64) ((float*)(sm + SCB))[tid] = cb[tid];
        __syncthreads();

        #pragma unroll
        for (int nt = 0; nt < 4; ++nt) {
            f32x4 acc = {0.f,0.f,0.f,0.f};
            #pragma unroll
            for (int ks = 0; ks < 2; ++ks) {
                short8 ah = *reinterpret_cast<const short8*>(
                    sm + XB + ((lane & 15) + 16 * wv) * 144 + (lane >> 4) * 16 + 64 * ks);
                short8 bw = *reinterpret_cast<const short8*>(
                    sm + CWT + ((lane & 15) + 16 * nt) * 144 + (lane >> 4) * 16 + 64 * ks);
                acc = MFMA(ah, bw, acc);
            }
            #pragma unroll
            for (int r4 = 0; r4 < 4; ++r4) {
                int w = (lane >> 4) * 4 + r4 + 16 * wv;
                int c = (lane & 15) + 16 * nt;
                float v = acc[r4] + ((const float*)(sm + SCB))[c];
                *(float*)(sm + OUTB + w * 272 + c * 4) = fmaxf(v, 0.0f);
            }
        }
        __syncthreads();

        float* orow = out + ((size_t)(b * NHt + h)) * (NWd * NC);
        #pragma unroll
        for (int i = 0; i < 4; ++i) {
            int flat = tid + 512 * i;
            int w = flat >> 4, c4 = (flat & 15) * 4;
            f32x4 v = *reinterpret_cast<const f32x4*>(sm + OUTB + w * 272 + c4 * 4);
            __builtin_nontemporal_store(v, reinterpret_cast<f32x4*>(orow + w * 64 + c4));
        }
    }
}

extern "C" void kernel_launch(void* const* d_in, const int* in_sizes, int n_in,
                              void* d_out, int out_size, void* d_ws, size_t ws_size,
                              hipStream_t stream) {
    const float* x      = (const float*)d_in[0];
    const float* w_real = (const float*)d_in[1];
    const float* w_imag = (const float*)d_in[2];
    const float* conv_w = (const float*)d_in[3];
    const float* conv_b = (const float*)d_in[4];
    float* out = (float*)d_out;

    char* tabs   = (char*)d_ws;
    ushort_t* XY = (ushort_t*)((char*)d_ws + XY_OFF);

    k1_fused<<<1024 + 2048, 512, 0, stream>>>(x, tabs, XY, conv_w, conv_b, out);
    k2_fused<<<1024 + 3072, 256, 0, stream>>>(w_real, w_imag, XY, x, conv_w, conv_b, out);
    k3_fused<<<1024 + 1024, 512, 0, stream>>>(x, conv_w, conv_b,
                                              (const char*)tabs, XY, out);
}